// Round 7
// baseline (246.129 us; speedup 1.0000x reference)
//
#include <hip/hip_runtime.h>
#include <hip/hip_bf16.h>

using bf16 = __hip_bfloat16;
using v8s = __attribute__((ext_vector_type(8))) short;   // MFMA A/B frag: 8 bf16
using v4f = __attribute__((ext_vector_type(4))) float;   // MFMA C/D frag

// Problem constants (from reference)
constexpr int kB = 4, kM = 64;
constexpr int kN2 = 512, kN1 = 2048, kN0 = 8192;
constexpr int kC2 = 256, kC1 = 128, kC0 = 64;

__device__ __forceinline__ float bs2f(unsigned short u) {
    return __uint_as_float((unsigned)u << 16);
}
__device__ __forceinline__ unsigned short f2bs(float f) {  // RNE fp32->bf16
    unsigned u = __float_as_uint(f);
    u += 0x7FFFu + ((u >> 16) & 1u);
    return (unsigned short)(u >> 16);
}
__device__ __forceinline__ float rdIn(const void* p, long i, int f32) {
    return f32 ? ((const float*)p)[i] : bs2f(((const unsigned short*)p)[i]);
}
__device__ __forceinline__ unsigned short rdBS(const void* p, long i, int f32) {
    return f32 ? f2bs(((const float*)p)[i]) : ((const unsigned short*)p)[i];
}
// load 8 consecutive elements as fp32 (16B-aligned offsets only)
__device__ __forceinline__ void ld8(const void* p, long off, int f32, float v[8]) {
    if (f32) {
        const float* fp = (const float*)p + off;
        float4 a = *(const float4*)fp;
        float4 b = *(const float4*)(fp + 4);
        v[0] = a.x; v[1] = a.y; v[2] = a.z; v[3] = a.w;
        v[4] = b.x; v[5] = b.y; v[6] = b.z; v[7] = b.w;
    } else {
        const unsigned short* hp = (const unsigned short*)p + off;
        uint4 u = *(const uint4*)hp;
        unsigned w[4] = {u.x, u.y, u.z, u.w};
        #pragma unroll
        for (int i = 0; i < 4; i++) {
            v[2 * i]     = bs2f((unsigned short)(w[i] & 0xFFFFu));
            v[2 * i + 1] = bs2f((unsigned short)(w[i] >> 16));
        }
    }
}
__device__ __forceinline__ uint4 pack8(const unsigned short o[8]) {
    uint4 u;
    u.x = (unsigned)o[0] | ((unsigned)o[1] << 16);
    u.y = (unsigned)o[2] | ((unsigned)o[3] << 16);
    u.z = (unsigned)o[4] | ((unsigned)o[5] << 16);
    u.w = (unsigned)o[6] | ((unsigned)o[7] << 16);
    return u;
}

// ===========================================================================
// dtype probe on `pos` (uniform [0,1)). flag: 1 = fp32, 0 = bf16.
// ===========================================================================
__global__ void fpno_probe_dtype(const unsigned int* __restrict__ w,
                                 int* __restrict__ flag) {
    __shared__ int sBad, sNz;
    if (threadIdx.x == 0) { sBad = 0; sNz = 0; }
    __syncthreads();
    int bad = 0, nz = 0;
    for (int j = 0; j < 2; j++) {
        unsigned lo = w[threadIdx.x + 256 * j] & 0xFFFFu;  // words 0..511 < 3072
        if (lo != 0u) { nz = 1; if ((lo & 0x8000u) || lo > 0x3F80u) bad = 1; }
    }
    if (bad) sBad = 1;
    if (nz) sNz = 1;
    __syncthreads();
    if (threadIdx.x == 0) *flag = (sBad || !sNz) ? 1 : 0;
}

// ===========================================================================
// one-time weight convert+transpose to bf16: WT[n][k] = W[k][n].
// ===========================================================================
__global__ void fpno_wconv(const void* __restrict__ W0a, const void* __restrict__ W0b,
                           const void* __restrict__ W1a, const void* __restrict__ W1b,
                           const int* __restrict__ flagp, unsigned short* __restrict__ WT) {
    const int f32 = *flagp;
    int tid = blockIdx.x * 256 + threadIdx.x;
    const void* src; int N, K; int base, local;
    if      (tid < 98304)  { src = W0a; N = 256; K = 384; base = 0;      local = tid; }
    else if (tid < 131072) { src = W0b; N = 128; K = 256; base = 98304;  local = tid - 98304; }
    else if (tid < 155648) { src = W1a; N = 128; K = 192; base = 131072; local = tid - 131072; }
    else if (tid < 163840) { src = W1b; N = 64;  K = 128; base = 155648; local = tid - 155648; }
    else return;
    int n = local / K, k = local % K;
    WT[base + local] = rdBS(src, (long)k * N + n, f32);
}

// ===========================================================================
// per-sample gate vectors
// ===========================================================================
__global__ void fpno_gates(const void* __restrict__ par,
                           const void* __restrict__ Wp0, const void* __restrict__ bp0,
                           const void* __restrict__ Wp1, const void* __restrict__ bp1,
                           const int* __restrict__ flagp,
                           float* __restrict__ g0, float* __restrict__ g1) {
    const int f32 = *flagp;
    int id = blockIdx.x * 256 + threadIdx.x;
    if (id < kB * 128) {
        int b = id / 128, n = id % 128;
        float a = rdIn(bp0, n, f32);
        for (int m = 0; m < kM; m++)
            a += rdIn(par, b * kM + m, f32) * rdIn(Wp0, m * 128 + n, f32);
        g0[id] = tanhf(a);
    } else if (id < kB * 128 + kB * 64) {
        int id2 = id - kB * 128;
        int b = id2 / 64, n = id2 % 64;
        float a = rdIn(bp1, n, f32);
        for (int m = 0; m < kM; m++)
            a += rdIn(par, b * kM + m, f32) * rdIn(Wp1, m * 64 + n, f32);
        g1[id2] = tanhf(a);
    }
}

// ===========================================================================
// kNN k=3, split-scan brute (proven) — kept for layer-1 (NS=512, small).
// ===========================================================================
template <int NS>
__global__ void fpno_nn3s(const void* __restrict__ srcP, const void* __restrict__ tgtP,
                          const int* __restrict__ flagp, int tgtPerSample,
                          int* __restrict__ oIdx, float* __restrict__ oW) {
    #pragma clang fp contract(off)
    constexpr int SPLIT = 8;
    constexpr int TPB = 256 / SPLIT;
    __shared__ float4 sp[NS];
    __shared__ float cd[256 * 3];
    __shared__ int   ci[256 * 3];
    const int f32 = *flagp;
    const int tid = threadIdx.x;
    const int tLoc = tid >> 3;
    const int spl  = tid & 7;
    const int tGlob = blockIdx.x * TPB + tLoc;
    const int smp = tGlob / tgtPerSample;
    for (int i = tid; i < NS; i += 256) {
        long b = (long)(smp * NS + i) * 3;
        sp[i] = make_float4(rdIn(srcP, b, f32), rdIn(srcP, b + 1, f32),
                            rdIn(srcP, b + 2, f32), 0.f);
    }
    __syncthreads();
    long tb = (long)tGlob * 3;
    float px = rdIn(tgtP, tb, f32), py = rdIn(tgtP, tb + 1, f32),
          pz = rdIn(tgtP, tb + 2, f32);
    float d0 = 1e30f, d1 = 1e30f, d2 = 1e30f;
    int i0 = 0x7FFFFFFF, i1 = 0x7FFFFFFF, i2 = 0x7FFFFFFF;
    for (int j = spl; j < NS; j += SPLIT) {
        float4 s = sp[j];
        float dx = px - s.x, dy = py - s.y, dz = pz - s.z;
        float d = ((dx * dx) + (dy * dy)) + (dz * dz);
        bool l0 = d < d0, l1 = d < d1, l2 = d < d2;
        float nd2 = l1 ? d1 : (l2 ? d : d2);
        int   ni2 = l1 ? i1 : (l2 ? j : i2);
        float nd1 = l0 ? d0 : (l1 ? d : d1);
        int   ni1 = l0 ? i0 : (l1 ? j : i1);
        float nd0 = l0 ? d : d0;
        int   ni0 = l0 ? j : i0;
        d2 = nd2; i2 = ni2; d1 = nd1; i1 = ni1; d0 = nd0; i0 = ni0;
    }
    cd[tid * 3 + 0] = d0; ci[tid * 3 + 0] = i0;
    cd[tid * 3 + 1] = d1; ci[tid * 3 + 1] = i1;
    cd[tid * 3 + 2] = d2; ci[tid * 3 + 2] = i2;
    __syncthreads();
    if (spl == 0) {
        float b0 = 1e30f, b1 = 1e30f, b2 = 1e30f;
        int k0 = 0x7FFFFFFF, k1 = 0x7FFFFFFF, k2 = 0x7FFFFFFF;
        int qb = tLoc * SPLIT * 3;
        for (int q = 0; q < SPLIT * 3; q++) {
            float d = cd[qb + q];
            int i = ci[qb + q];
            if ((d < b2) || (d == b2 && i < k2)) {
                if ((d < b1) || (d == b1 && i < k1)) {
                    b2 = b1; k2 = k1;
                    if ((d < b0) || (d == b0 && i < k0)) { b1 = b0; k1 = k0; b0 = d; k0 = i; }
                    else                                  { b1 = d;  k1 = i; }
                } else { b2 = d; k2 = i; }
            }
        }
        float wa = 1.f / fmaxf(b0, 1e-16f);
        float wb = 1.f / fmaxf(b1, 1e-16f);
        float wc = 1.f / fmaxf(b2, 1e-16f);
        float s = wa + wb + wc;
        oIdx[tGlob * 3 + 0] = smp * NS + k0;
        oIdx[tGlob * 3 + 1] = smp * NS + k1;
        oIdx[tGlob * 3 + 2] = smp * NS + k2;
        oW[tGlob * 3 + 0] = wa / s;
        oW[tGlob * 3 + 1] = wb / s;
        oW[tGlob * 3 + 2] = wc / s;
    }
}

// ===========================================================================
// Grid-bucket build: bins NS points of one sample into G^3 cells.
// ===========================================================================
template <int NS, int G, int TPB>
__global__ void fpno_bin(const void* __restrict__ srcP, const int* __restrict__ flagp,
                         float4* __restrict__ pts, int* __restrict__ cellStart) {
    constexpr int G3 = G * G * G;
    constexpr int PPT = NS / TPB;
    __shared__ int cnt[G3];
    __shared__ int sc[G3];
    __shared__ int cur[G3];
    const int f32 = *flagp;
    const int smp = blockIdx.x, tid = threadIdx.x;
    for (int i = tid; i < G3; i += TPB) cnt[i] = 0;
    __syncthreads();
    float4 p[PPT]; int cl[PPT];
    #pragma unroll
    for (int r = 0; r < PPT; r++) {
        int j = r * TPB + tid;
        long b = ((long)smp * NS + j) * 3;
        float x = rdIn(srcP, b, f32), y = rdIn(srcP, b + 1, f32), z = rdIn(srcP, b + 2, f32);
        int cx = min(G - 1, max(0, (int)(x * (float)G)));
        int cy = min(G - 1, max(0, (int)(y * (float)G)));
        int cz = min(G - 1, max(0, (int)(z * (float)G)));
        cl[r] = (cz * G + cy) * G + cx;
        p[r] = make_float4(x, y, z, __int_as_float(j));
        atomicAdd(&cnt[cl[r]], 1);
    }
    __syncthreads();
    int v = (tid < G3) ? cnt[tid] : 0;
    if (tid < G3) sc[tid] = v;
    __syncthreads();
    for (int ofs = 1; ofs < G3; ofs <<= 1) {
        int t = 0;
        if (tid < G3 && tid >= ofs) t = sc[tid - ofs];
        __syncthreads();
        if (tid < G3) sc[tid] += t;
        __syncthreads();
    }
    if (tid < G3) {
        int st = sc[tid] - v;
        cur[tid] = st;
        cellStart[smp * (G3 + 1) + tid] = st;
    }
    if (tid == 0) cellStart[smp * (G3 + 1) + G3] = NS;
    __syncthreads();
    #pragma unroll
    for (int r = 0; r < PPT; r++) {
        int slot = atomicAdd(&cur[cl[r]], 1);
        pts[(long)smp * NS + slot] = p[r];
    }
}

// ===========================================================================
// Grid-pruned exact kNN k=3, lockstep + 8-way split + shuffle merge (proven
// round 6: 410->244 total). See round-5/6 notes for exactness argument.
// ===========================================================================
template <int NS, int NT, int G, int SPLIT>
__global__ void fpno_nngs(const float4* __restrict__ pts, const int* __restrict__ cellStart,
                          const float4* __restrict__ ptsT,
                          int* __restrict__ oIdx, float* __restrict__ oW) {
    #pragma clang fp contract(off)
    constexpr int G3 = G * G * G;
    constexpr float h = 1.0f / (float)G;
    constexpr int TPT = 256 / SPLIT;
    constexpr int BPS = NT / TPT;
    __shared__ float4 sp[NS];
    __shared__ int cs[G3 + 1];
    const int tid = threadIdx.x;
    const int tLoc = tid >> 3;
    const int spl  = tid & (SPLIT - 1);
    const int smp = blockIdx.x / BPS;
    const int blk = blockIdx.x % BPS;
    for (int i = tid; i < NS; i += 256) sp[i] = pts[(long)smp * NS + i];
    for (int i = tid; i < G3 + 1; i += 256) cs[i] = cellStart[smp * (G3 + 1) + i];
    __syncthreads();

    float4 q = ptsT[(long)smp * NT + blk * TPT + tLoc];
    float px = q.x, py = q.y, pz = q.z;
    const int jloc = __float_as_int(q.w);
    int cx = min(G - 1, max(0, (int)(px * (float)G)));
    int cy = min(G - 1, max(0, (int)(py * (float)G)));
    int cz = min(G - 1, max(0, (int)(pz * (float)G)));
    float d0 = 1e30f, d1 = 1e30f, d2 = 1e30f;
    int i0 = 0x7FFFFFFF, i1 = 0x7FFFFFFF, i2 = 0x7FFFFFFF;

    auto insert = [&](float d, int j) {
        bool l0 = (d < d0) || (d == d0 && j < i0);
        bool l1 = (d < d1) || (d == d1 && j < i1);
        bool l2 = (d < d2) || (d == d2 && j < i2);
        float nd2 = l1 ? d1 : (l2 ? d : d2);
        int   ni2 = l1 ? i1 : (l2 ? j : i2);
        float nd1 = l0 ? d0 : (l1 ? d : d1);
        int   ni1 = l0 ? i0 : (l1 ? j : i1);
        d2 = nd2; i2 = ni2; d1 = nd1; i1 = ni1;
        d0 = l0 ? d : d0; i0 = l0 ? j : i0;
    };
    auto scanCell = [&](int cell) {
        int s = cs[cell], e = cs[cell + 1];
        for (int t = s + spl; t < e; t += SPLIT) {
            float4 c = sp[t];
            int j = __float_as_int(c.w);
            float dx = px - c.x, dy = py - c.y, dz = pz - c.z;
            float d = ((dx * dx) + (dy * dy)) + (dz * dz);
            insert(d, j);
        }
    };
    auto merge8 = [&]() {
        #pragma unroll
        for (int m = 1; m < SPLIT; m <<= 1) {
            float pd0 = __shfl_xor(d0, m), pd1 = __shfl_xor(d1, m), pd2 = __shfl_xor(d2, m);
            int   pi0 = __shfl_xor(i0, m), pi1 = __shfl_xor(i1, m), pi2 = __shfl_xor(i2, m);
            if (pi0 != i0 && pi0 != i1 && pi0 != i2) insert(pd0, pi0);
            if (pi1 != i0 && pi1 != i1 && pi1 != i2) insert(pd1, pi1);
            if (pi2 != i0 && pi2 != i1 && pi2 != i2) insert(pd2, pi2);
        }
    };

    #pragma unroll 1
    for (int o = 0; o < 27; o++) {
        int ox = o % 3 - 1, oy = (o / 3) % 3 - 1, oz = o / 9 - 1;
        int X = cx + ox, Y = cy + oy, Z = cz + oz;
        if (X < 0 || X >= G || Y < 0 || Y >= G || Z < 0 || Z >= G) continue;
        scanCell((Z * G + Y) * G + X);
    }
    merge8();

    #pragma unroll 1
    for (int s = 2; s < G; s++) {
        float rm = ((float)(s - 1) * h);
        float ringMin = rm * rm * 0.9999f;
        if (d2 < ringMin) break;
        #pragma unroll 1
        for (int oz = -s; oz <= s; oz++) {
            int Z = cz + oz; if (Z < 0 || Z >= G) continue;
            int az = oz < 0 ? -oz : oz;
            #pragma unroll 1
            for (int oy = -s; oy <= s; oy++) {
                int Y = cy + oy; if (Y < 0 || Y >= G) continue;
                int ay = oy < 0 ? -oy : oy;
                bool outer = (az == s) || (ay == s);
                #pragma unroll 1
                for (int ox = -s; ox <= s; ox++) {
                    int ax = ox < 0 ? -ox : ox;
                    if (!outer && ax != s) continue;
                    int X = cx + ox; if (X < 0 || X >= G) continue;
                    float lx = (float)X * h, ly = (float)Y * h, lz = (float)Z * h;
                    float ex = fmaxf(0.f, fmaxf(lx - px, px - (lx + h)));
                    float ey = fmaxf(0.f, fmaxf(ly - py, py - (ly + h)));
                    float ez = fmaxf(0.f, fmaxf(lz - pz, pz - (lz + h)));
                    float md = ((ex * ex) + (ey * ey)) + (ez * ez);
                    if (md * 0.9999f > d2) continue;
                    scanCell((Z * G + Y) * G + X);
                }
            }
        }
        merge8();
    }

    if (spl == 0) {
        float wa = 1.f / fmaxf(d0, 1e-16f);
        float wb = 1.f / fmaxf(d1, 1e-16f);
        float wc = 1.f / fmaxf(d2, 1e-16f);
        float sw = wa + wb + wc;
        long tg = (long)smp * NT + jloc;
        oIdx[tg * 3 + 0] = smp * NS + i0;
        oIdx[tg * 3 + 1] = smp * NS + i1;
        oIdx[tg * 3 + 2] = smp * NS + i2;
        oW[tg * 3 + 0] = wa / sw;
        oW[tg * 3 + 1] = wb / sw;
        oW[tg * 3 + 2] = wc / sw;
    }
}

// ===========================================================================
// NEW: materialize Xcat = [interp(feats) | skip] as bf16 (one 16B write per
// thread, fully parallel, no barriers). Kills the bn-redundant gathers that
// were re-done per column-block inside the old fused mf_a (round-6 theory:
// MFMA stages ~40us each from barrier-serialized gather latency).
// ===========================================================================
template <int CF, int CS>
__global__ void fpno_interp(const void* __restrict__ feats_raw,
                            const unsigned short* __restrict__ featsBF,
                            const void* __restrict__ skip_raw,
                            const int* __restrict__ idx, const float* __restrict__ wgt,
                            const int* __restrict__ flagp,
                            unsigned short* __restrict__ XC, int rows) {
    constexpr int KD = CF + CS;
    constexpr int CH = KD / 8;
    const int f32 = *flagp;
    int gid = blockIdx.x * 256 + threadIdx.x;
    if (gid >= rows * CH) return;
    int row = gid / CH, c0 = (gid % CH) * 8;
    unsigned short o[8];
    if (c0 < CF) {
        int j0 = idx[row * 3 + 0], j1 = idx[row * 3 + 1], j2 = idx[row * 3 + 2];
        float w0 = wgt[row * 3 + 0], w1 = wgt[row * 3 + 1], w2 = wgt[row * 3 + 2];
        const void* fsrc = featsBF ? (const void*)featsBF : feats_raw;
        const int ff32 = featsBF ? 0 : f32;
        float a0[8], a1[8], a2[8];
        ld8(fsrc, (long)j0 * CF + c0, ff32, a0);
        ld8(fsrc, (long)j1 * CF + c0, ff32, a1);
        ld8(fsrc, (long)j2 * CF + c0, ff32, a2);
        #pragma unroll
        for (int j = 0; j < 8; j++)
            o[j] = f2bs(w0 * a0[j] + w1 * a1[j] + w2 * a2[j]);
    } else {
        float s8[8];
        ld8(skip_raw, (long)row * CS + (c0 - CF), f32, s8);
        #pragma unroll
        for (int j = 0; j < 8; j++) o[j] = f2bs(s8[j]);
    }
    *(uint4*)&XC[(long)row * KD + c0] = pack8(o);
}

// ===========================================================================
// NEW: barrier-minimal GEMM: Y[64xNd tile] = act(A @ W + b) [* gate].
// Full 64xKD A-tile staged via KD/32 INDEPENDENT uint4 copies (each thread
// writes its own LDS slot -> no inter-chunk barriers), ONE __syncthreads,
// then a barrier-free MFMA loop (B-frags stream from L2-resident WT).
// Old structure had 2 barriers per 32-k chunk = latency fully serialized.
// ===========================================================================
template <int KD, bool TANH, bool OUTBF, int SMPSHIFT, bool GATED>
__global__ void fpno_gemm(const unsigned short* __restrict__ A,
                          const unsigned short* __restrict__ WT,
                          const void* __restrict__ bv,
                          const float* __restrict__ gate,
                          const int* __restrict__ flagp,
                          void* __restrict__ Y, int Nd) {
    constexpr int LDA = KD + 8;    // +16B pad: dword-stride != 0 mod 32
    __shared__ unsigned short As[64 * LDA];
    const int f32 = *flagp;
    const int tid = threadIdx.x;
    const int lane = tid & 63, wv = tid >> 6;
    const int l16 = lane & 15, quad = lane >> 4;
    const int bm = blockIdx.x, bn = blockIdx.y;
    const int row = tid >> 2, seg = tid & 3;

    // stage full A tile: independent copies, no inner barriers
    #pragma unroll
    for (int k0 = 0; k0 < KD; k0 += 32) {
        uint4 hv = *(const uint4*)&A[(long)(bm * 64 + row) * KD + k0 + seg * 8];
        *(uint4*)&As[row * LDA + k0 + seg * 8] = hv;
    }
    __syncthreads();

    v4f acc[4];
    #pragma unroll
    for (int t = 0; t < 4; t++) acc[t] = (v4f){0.f, 0.f, 0.f, 0.f};

    #pragma unroll 1
    for (int k0 = 0; k0 < KD; k0 += 32) {
        const v8s a = *(const v8s*)&As[(wv * 16 + l16) * LDA + k0 + quad * 8];
        long kg = (long)(k0 + quad * 8);
        #pragma unroll
        for (int t = 0; t < 4; t++) {
            int colg = bn * 64 + t * 16 + l16;
            const v8s b = *(const v8s*)&WT[(long)colg * KD + kg];
            acc[t] = __builtin_amdgcn_mfma_f32_16x16x32_bf16(a, b, acc[t], 0, 0, 0);
        }
    }

    #pragma unroll
    for (int t = 0; t < 4; t++) {
        int c = bn * 64 + t * 16 + l16;
        float bb = rdIn(bv, c, f32);
        #pragma unroll
        for (int i = 0; i < 4; i++) {
            int r = bm * 64 + wv * 16 + quad * 4 + i;
            float v = acc[t][i] + bb;
            if (TANH) v = tanhf(v);
            if (GATED) v *= gate[(r >> SMPSHIFT) * Nd + c];
            if (OUTBF) ((unsigned short*)Y)[(long)r * Nd + c] = f2bs(v);
            else       ((float*)Y)[(long)r * Nd + c] = v;
        }
    }
}

// ===========================================================================
// output tail (fp32): [pos_skip_l0 (32768*3) | batch_skip_l0 (32768)]
// ===========================================================================
__global__ void fpno_tail(const void* __restrict__ pos0, const int* __restrict__ bt0,
                          const int* __restrict__ flagp, float* __restrict__ out) {
    const int f32 = *flagp;
    int id = blockIdx.x * 256 + threadIdx.x;  // 0..131071
    const int nX = kB * kN0 * kC0;   // 2097152
    const int nP = kB * kN0 * 3;     // 98304
    if (id < nP) out[nX + id] = rdIn(pos0, id, f32);
    else         out[nX + id] = (float)bt0[id - nP];
}

__global__ void fpno_guard(float code, float* __restrict__ out) {
    if (threadIdx.x == 0) out[0] = code;
}

// ===========================================================================
extern "C" void kernel_launch(void* const* d_in, const int* in_sizes, int n_in,
                              void* d_out, int out_size, void* d_ws, size_t ws_size,
                              hipStream_t stream) {
    (void)out_size;
    float* out = (float*)d_out;   // fp32 output buffer
    const int R1 = kB * kN1;  // 8192
    const int R0 = kB * kN0;  // 32768

    static const int kExp[22] = {
        256, 524288, 6144, 2048, 1048576, 24576, 8192, 2097152, 98304, 32768,
        98304, 256, 32768, 128, 8192, 128, 24576, 128, 8192, 64, 4096, 64};
    if (n_in != 22) { fpno_guard<<<1, 64, 0, stream>>>(3072.0f, out); return; }
    for (int i = 0; i < 22; i++) {
        if (in_sizes[i] != kExp[i]) {
            fpno_guard<<<1, 64, 0, stream>>>(1024.0f + 8.0f * i, out);
            return;
        }
    }

    // ---- workspace (~33 MB) ----
    char* base = (char*)d_ws;
    size_t off = 0;
    auto alloc = [&](size_t bytes) {
        off = (off + 255) & ~(size_t)255; size_t o = off; off += bytes; return o;
    };
    int*            flag = (int*)(base + alloc(4));
    float*          g0   = (float*)(base + alloc(kB * 128 * 4));
    float*          g1   = (float*)(base + alloc(kB * 64 * 4));
    int*            i1d  = (int*)(base + alloc((size_t)R1 * 3 * 4));
    float*          w1d  = (float*)(base + alloc((size_t)R1 * 3 * 4));
    int*            i0d  = (int*)(base + alloc((size_t)R0 * 3 * 4));
    float*          w0d  = (float*)(base + alloc((size_t)R0 * 3 * 4));
    float4*         ptsG = (float4*)(base + alloc((size_t)kB * kN1 * 16));          // 128 KB
    int*            cstG = (int*)(base + alloc((size_t)kB * (512 + 1) * 4));
    float4*         ptsT = (float4*)(base + alloc((size_t)kB * kN0 * 16));          // 512 KB
    int*            cstT = (int*)(base + alloc((size_t)kB * (512 + 1) * 4));
    unsigned short* WT   = (unsigned short*)(base + alloc(163840 * 2));             // 320 KB
    unsigned short* XC1  = (unsigned short*)(base + alloc((size_t)R1 * 384 * 2));   // 6 MB
    unsigned short* H1   = (unsigned short*)(base + alloc((size_t)R1 * 256 * 2));   // 4 MB
    unsigned short* X1   = (unsigned short*)(base + alloc((size_t)R1 * 128 * 2));   // 2 MB
    unsigned short* XC2  = (unsigned short*)(base + alloc((size_t)R0 * 192 * 2));   // 12 MB
    unsigned short* H2   = (unsigned short*)(base + alloc((size_t)R0 * 128 * 2));   // 8 MB
    if (ws_size < off) { fpno_guard<<<1, 64, 0, stream>>>(2048.0f, out); return; }
    unsigned short* WT0a = WT;            // 256 x 384
    unsigned short* WT0b = WT + 98304;    // 128 x 256
    unsigned short* WT1a = WT + 131072;   // 128 x 192
    unsigned short* WT1b = WT + 155648;   // 64 x 128

    const void* par  = d_in[0];
    const void* x    = d_in[1];
    const void* pos  = d_in[2];
    const void* xs1  = d_in[4];
    const void* pos1 = d_in[5];
    const void* xs0  = d_in[7];
    const void* pos0 = d_in[8];
    const int*  bt0  = (const int*)d_in[9];
    const void *W0a = d_in[10], *b0a = d_in[11], *W0b = d_in[12], *b0b = d_in[13];
    const void *Wp0 = d_in[14], *bp0 = d_in[15];
    const void *W1a = d_in[16], *b1a = d_in[17], *W1b = d_in[18], *b1b = d_in[19];
    const void *Wp1 = d_in[20], *bp1 = d_in[21];

    // 1) input dtype probe
    fpno_probe_dtype<<<1, 256, 0, stream>>>((const unsigned int*)pos, flag);

    // 2) weight transpose/convert (one-time, 320 KB, L2-resident thereafter)
    fpno_wconv<<<640, 256, 0, stream>>>(W0a, W0b, W1a, W1b, flag, WT);

    // 3) per-sample gates
    fpno_gates<<<3, 256, 0, stream>>>(par, Wp0, bp0, Wp1, bp1, flag, g0, g1);

    // 4) layer-1 kNN (brute, small)
    fpno_nn3s<kN2><<<R1 / 32, 256, 0, stream>>>(pos, pos1, flag, kN1, i1d, w1d);

    // 4b) layer-2 source grid + target sort
    fpno_bin<kN1, 8, 512><<<kB, 512, 0, stream>>>(pos1, flag, ptsG, cstG);
    fpno_bin<kN0, 8, 512><<<kB, 512, 0, stream>>>(pos0, flag, ptsT, cstT);

    // 5a) XC1 = [interp(x), xs1]  (8192 x 384 bf16)
    fpno_interp<kC2, kC1><<<(R1 * 48 + 255) / 256, 256, 0, stream>>>(
        x, nullptr, xs1, i1d, w1d, flag, XC1, R1);

    // 5b) H1 = tanh(XC1 @ W0a + b0a)          8192x384 @ 384x256
    fpno_gemm<384, true, true, 0, false><<<dim3(R1 / 64, 4), 256, 0, stream>>>(
        XC1, WT0a, b0a, nullptr, flag, H1, 256);

    // 6) X1 = tanh(H1 @ W0b + b0b) * g0       8192x256 @ 256x128
    fpno_gemm<256, true, true, 11, true><<<dim3(R1 / 64, 2), 256, 0, stream>>>(
        H1, WT0b, b0b, g0, flag, X1, 128);

    // 7) layer-2 kNN: cell-sorted grid scan + shuffle merge
    fpno_nngs<kN1, kN0, 8, 8><<<kB * kN0 / 32, 256, 0, stream>>>(
        ptsG, cstG, ptsT, i0d, w0d);

    // 8a) XC2 = [interp(X1), xs0]  (32768 x 192 bf16)
    fpno_interp<kC1, kC0><<<(R0 * 24 + 255) / 256, 256, 0, stream>>>(
        nullptr, X1, xs0, i0d, w0d, flag, XC2, R0);

    // 8b) H2 = tanh(XC2 @ W1a + b1a)          32768x192 @ 192x128
    fpno_gemm<192, true, true, 0, false><<<dim3(R0 / 64, 2), 256, 0, stream>>>(
        XC2, WT1a, b1a, nullptr, flag, H2, 128);

    // 9) x0 = (H2 @ W1b + b1b) * g1 -> fp32   32768x128 @ 128x64
    fpno_gemm<128, false, false, 13, true><<<dim3(R0 / 64, 1), 256, 0, stream>>>(
        H2, WT1b, b1b, g1, flag, out, 64);

    // 10) tail passthrough (fp32)
    fpno_tail<<<(kB * kN0 * 4) / 256, 256, 0, stream>>>(pos0, bt0, flag, out);
}

// Round 8
// 217.975 us; speedup vs baseline: 1.1292x; 1.1292x over previous
//
#include <hip/hip_runtime.h>
#include <hip/hip_bf16.h>

using bf16 = __hip_bfloat16;
using v8s = __attribute__((ext_vector_type(8))) short;   // MFMA A/B frag: 8 bf16
using v4f = __attribute__((ext_vector_type(4))) float;   // MFMA C/D frag

// Problem constants (from reference)
constexpr int kB = 4, kM = 64;
constexpr int kN2 = 512, kN1 = 2048, kN0 = 8192;
constexpr int kC2 = 256, kC1 = 128, kC0 = 64;

__device__ __forceinline__ float bs2f(unsigned short u) {
    return __uint_as_float((unsigned)u << 16);
}
__device__ __forceinline__ unsigned short f2bs(float f) {  // RNE fp32->bf16
    unsigned u = __float_as_uint(f);
    u += 0x7FFFu + ((u >> 16) & 1u);
    return (unsigned short)(u >> 16);
}
__device__ __forceinline__ float rdIn(const void* p, long i, int f32) {
    return f32 ? ((const float*)p)[i] : bs2f(((const unsigned short*)p)[i]);
}
__device__ __forceinline__ unsigned short rdBS(const void* p, long i, int f32) {
    return f32 ? f2bs(((const float*)p)[i]) : ((const unsigned short*)p)[i];
}
// load 8 consecutive elements as fp32 (16B-aligned offsets only)
__device__ __forceinline__ void ld8(const void* p, long off, int f32, float v[8]) {
    if (f32) {
        const float* fp = (const float*)p + off;
        float4 a = *(const float4*)fp;
        float4 b = *(const float4*)(fp + 4);
        v[0] = a.x; v[1] = a.y; v[2] = a.z; v[3] = a.w;
        v[4] = b.x; v[5] = b.y; v[6] = b.z; v[7] = b.w;
    } else {
        const unsigned short* hp = (const unsigned short*)p + off;
        uint4 u = *(const uint4*)hp;
        unsigned w[4] = {u.x, u.y, u.z, u.w};
        #pragma unroll
        for (int i = 0; i < 4; i++) {
            v[2 * i]     = bs2f((unsigned short)(w[i] & 0xFFFFu));
            v[2 * i + 1] = bs2f((unsigned short)(w[i] >> 16));
        }
    }
}
__device__ __forceinline__ uint4 pack8(const unsigned short o[8]) {
    uint4 u;
    u.x = (unsigned)o[0] | ((unsigned)o[1] << 16);
    u.y = (unsigned)o[2] | ((unsigned)o[3] << 16);
    u.z = (unsigned)o[4] | ((unsigned)o[5] << 16);
    u.w = (unsigned)o[6] | ((unsigned)o[7] << 16);
    return u;
}

__global__ void fpno_guard(float code, float* __restrict__ out) {
    if (threadIdx.x == 0) out[0] = code;
}

// ===========================================================================
// PHASE 1 (one launch, 512 thr): wconv | gates | layer-1 kNN | bin x2 | tail.
// All jobs independent. Each block inlines the dtype probe (same 512 words,
// same predicate as the old fpno_probe_dtype) -> no flag dependency inside
// the kernel; block 0 also writes the flag for phases 2/3.
// Round-7 lesson: 4 different kernel structures all measured 244-246us ->
// ~175us fixed cost ~ 14-deep dependent launch chain. This build = 3 launches.
// ===========================================================================
__global__ __launch_bounds__(512) void fpno_p1(
    const unsigned int* __restrict__ posW,     // pos as words (probe)
    const void* __restrict__ pos,              // layer-1 kNN sources
    const void* __restrict__ pos1,             // layer-1 targets / layer-2 sources
    const void* __restrict__ pos0,             // layer-2 targets / tail
    const void* __restrict__ W0a, const void* __restrict__ W0b,
    const void* __restrict__ W1a, const void* __restrict__ W1b,
    const void* __restrict__ par,
    const void* __restrict__ Wp0, const void* __restrict__ bp0,
    const void* __restrict__ Wp1, const void* __restrict__ bp1,
    const int* __restrict__ bt0,
    int* __restrict__ flag, unsigned short* __restrict__ WT,
    float* __restrict__ g0, float* __restrict__ g1,
    int* __restrict__ i1d, float* __restrict__ w1d,
    float4* __restrict__ ptsG, int* __restrict__ cstG,
    float4* __restrict__ ptsT, int* __restrict__ cstT,
    float* __restrict__ out) {
    #pragma clang fp contract(off)
    __shared__ __align__(16) char smem[20480];
    __shared__ int sflg[2];
    const int b = blockIdx.x, tid = threadIdx.x;

    // ---- inline dtype probe (identical word set + predicate as before) ----
    if (tid == 0) { sflg[0] = 0; sflg[1] = 0; }
    __syncthreads();
    {
        unsigned lo = posW[tid] & 0xFFFFu;   // words 0..511
        int bad = 0, nz = 0;
        if (lo != 0u) { nz = 1; if ((lo & 0x8000u) || lo > 0x3F80u) bad = 1; }
        if (bad) sflg[0] = 1;
        if (nz) sflg[1] = 1;
    }
    __syncthreads();
    const int f32 = (sflg[0] || !sflg[1]) ? 1 : 0;
    if (b == 0 && tid == 0) *flag = f32;

    if (b < 320) {
        // ---- weight transpose/convert ----
        int id = b * 512 + tid;
        const void* src; int N, K; int base, local;
        if      (id < 98304)  { src = W0a; N = 256; K = 384; base = 0;      local = id; }
        else if (id < 131072) { src = W0b; N = 128; K = 256; base = 98304;  local = id - 98304; }
        else if (id < 155648) { src = W1a; N = 128; K = 192; base = 131072; local = id - 131072; }
        else                  { src = W1b; N = 64;  K = 128; base = 155648; local = id - 155648; }
        int n = local / K, k = local % K;
        WT[base + local] = rdBS(src, (long)k * N + n, f32);
    } else if (b < 322) {
        // ---- gates ----
        int id = (b - 320) * 512 + tid;
        if (id < kB * 128) {
            int bb = id / 128, n = id % 128;
            float a = rdIn(bp0, n, f32);
            for (int m = 0; m < kM; m++)
                a += rdIn(par, bb * kM + m, f32) * rdIn(Wp0, m * 128 + n, f32);
            g0[id] = tanhf(a);
        } else if (id < kB * 128 + kB * 64) {
            int id2 = id - kB * 128;
            int bb = id2 / 64, n = id2 % 64;
            float a = rdIn(bp1, n, f32);
            for (int m = 0; m < kM; m++)
                a += rdIn(par, bb * kM + m, f32) * rdIn(Wp1, m * 64 + n, f32);
            g1[id2] = tanhf(a);
        }
    } else if (b < 450) {
        // ---- layer-1 kNN brute (proven): 64 targets x 8 splits ----
        constexpr int NS = kN2;                         // 512 sources/sample
        float4* sp = (float4*)smem;                     // 8192 B
        float*  cd = (float*)(smem + 8192);             // 6144 B
        int*    ci = (int*)(smem + 14336);              // 6144 B
        const int blk = b - 322;
        const int tLoc = tid >> 3;                      // 0..63
        const int spl  = tid & 7;
        const int tGlob = blk * 64 + tLoc;              // 0..8191
        const int smp = tGlob / kN1;
        for (int i = tid; i < NS; i += 512) {
            long bb = (long)(smp * NS + i) * 3;
            sp[i] = make_float4(rdIn(pos, bb, f32), rdIn(pos, bb + 1, f32),
                                rdIn(pos, bb + 2, f32), 0.f);
        }
        __syncthreads();
        long tb = (long)tGlob * 3;
        float px = rdIn(pos1, tb, f32), py = rdIn(pos1, tb + 1, f32),
              pz = rdIn(pos1, tb + 2, f32);
        float d0 = 1e30f, d1 = 1e30f, d2 = 1e30f;
        int i0 = 0x7FFFFFFF, i1 = 0x7FFFFFFF, i2 = 0x7FFFFFFF;
        for (int j = spl; j < NS; j += 8) {
            float4 s = sp[j];
            float dx = px - s.x, dy = py - s.y, dz = pz - s.z;
            float d = ((dx * dx) + (dy * dy)) + (dz * dz);
            bool l0 = d < d0, l1 = d < d1, l2 = d < d2;
            float nd2 = l1 ? d1 : (l2 ? d : d2);
            int   ni2 = l1 ? i1 : (l2 ? j : i2);
            float nd1 = l0 ? d0 : (l1 ? d : d1);
            int   ni1 = l0 ? i0 : (l1 ? j : i1);
            float nd0 = l0 ? d : d0;
            int   ni0 = l0 ? j : i0;
            d2 = nd2; i2 = ni2; d1 = nd1; i1 = ni1; d0 = nd0; i0 = ni0;
        }
        cd[tid * 3 + 0] = d0; ci[tid * 3 + 0] = i0;
        cd[tid * 3 + 1] = d1; ci[tid * 3 + 1] = i1;
        cd[tid * 3 + 2] = d2; ci[tid * 3 + 2] = i2;
        __syncthreads();
        if (spl == 0) {
            float b0 = 1e30f, b1 = 1e30f, b2 = 1e30f;
            int k0 = 0x7FFFFFFF, k1 = 0x7FFFFFFF, k2 = 0x7FFFFFFF;
            int qb = tLoc * 24;
            for (int q = 0; q < 24; q++) {
                float d = cd[qb + q];
                int i = ci[qb + q];
                if ((d < b2) || (d == b2 && i < k2)) {
                    if ((d < b1) || (d == b1 && i < k1)) {
                        b2 = b1; k2 = k1;
                        if ((d < b0) || (d == b0 && i < k0)) { b1 = b0; k1 = k0; b0 = d; k0 = i; }
                        else                                  { b1 = d;  k1 = i; }
                    } else { b2 = d; k2 = i; }
                }
            }
            float wa = 1.f / fmaxf(b0, 1e-16f);
            float wb = 1.f / fmaxf(b1, 1e-16f);
            float wc = 1.f / fmaxf(b2, 1e-16f);
            float s = wa + wb + wc;
            i1d[tGlob * 3 + 0] = smp * NS + k0;
            i1d[tGlob * 3 + 1] = smp * NS + k1;
            i1d[tGlob * 3 + 2] = smp * NS + k2;
            w1d[tGlob * 3 + 0] = wa / s;
            w1d[tGlob * 3 + 1] = wb / s;
            w1d[tGlob * 3 + 2] = wc / s;
        }
    } else if (b < 458) {
        // ---- grid binning: b<454 -> sources (pos1, 2048); else targets (pos0, 8192) ----
        constexpr int G3 = 512;
        int* cnt = (int*)smem;
        int* sc  = cnt + G3;
        int* cur = sc + G3;
        const bool srcSide = (b < 454);
        const int smp = srcSide ? (b - 450) : (b - 454);
        const int NSb = srcSide ? kN1 : kN0;
        const int PPT = NSb / 512;
        const void* P = srcSide ? pos1 : pos0;
        float4* pts = srcSide ? ptsG : ptsT;
        int* cstart = srcSide ? cstG : cstT;
        for (int i = tid; i < G3; i += 512) cnt[i] = 0;
        __syncthreads();
        float4 p[16]; int cl[16];
        for (int r = 0; r < PPT; r++) {
            int j = r * 512 + tid;
            long bb = ((long)smp * NSb + j) * 3;
            float x = rdIn(P, bb, f32), y = rdIn(P, bb + 1, f32), z = rdIn(P, bb + 2, f32);
            int cx = min(7, max(0, (int)(x * 8.f)));
            int cy = min(7, max(0, (int)(y * 8.f)));
            int cz = min(7, max(0, (int)(z * 8.f)));
            cl[r] = (cz * 8 + cy) * 8 + cx;
            p[r] = make_float4(x, y, z, __int_as_float(j));
            atomicAdd(&cnt[cl[r]], 1);
        }
        __syncthreads();
        int v = cnt[tid];
        sc[tid] = v;
        __syncthreads();
        for (int ofs = 1; ofs < G3; ofs <<= 1) {
            int t = 0;
            if (tid >= ofs) t = sc[tid - ofs];
            __syncthreads();
            sc[tid] += t;
            __syncthreads();
        }
        {
            int st = sc[tid] - v;
            cur[tid] = st;
            cstart[smp * (G3 + 1) + tid] = st;
        }
        if (tid == 0) cstart[smp * (G3 + 1) + G3] = NSb;
        __syncthreads();
        for (int r = 0; r < PPT; r++) {
            int slot = atomicAdd(&cur[cl[r]], 1);
            pts[(long)smp * NSb + slot] = p[r];
        }
    } else {
        // ---- output tail ----
        int id = (b - 458) * 512 + tid;          // 0..131071
        const int nX = kB * kN0 * kC0;           // 2097152
        const int nP = kB * kN0 * 3;             // 98304
        if (id < nP) out[nX + id] = rdIn(pos0, id, f32);
        else         out[nX + id] = (float)bt0[id - nP];
    }
}

// ===========================================================================
// PHASE 2 (one launch, 256 thr):
//   blocks [0,128):      fused layer-1 MLP on a 64-row slab:
//                        gather-interp -> LDS, GEMM K=384 -> tanh -> LDS,
//                        GEMM K=256 -> tanh*g0 -> X1 (bf16). H1 never global.
//   blocks [128,1152):   layer-2 grid kNN (proven shuffle-merge, round 6).
// ===========================================================================
__global__ __launch_bounds__(256) void fpno_p2(
    const void* __restrict__ x, const void* __restrict__ xs1,
    const unsigned short* __restrict__ WT0a, const unsigned short* __restrict__ WT0b,
    const void* __restrict__ b0a, const void* __restrict__ b0b,
    const float* __restrict__ g0,
    const int* __restrict__ i1d, const float* __restrict__ w1d,
    const float4* __restrict__ ptsG, const int* __restrict__ cstG,
    const float4* __restrict__ ptsT,
    const int* __restrict__ flagp,
    unsigned short* __restrict__ X1,
    int* __restrict__ i0d, float* __restrict__ w0d) {
    #pragma clang fp contract(off)
    __shared__ __align__(16) char smem[50176];
    const int f32 = *flagp;
    const int tid = threadIdx.x;

    if (blockIdx.x < 128) {
        // ================= fused layer-1 MLP =================
        constexpr int LDX = 392;   // 384 + 8 pad (halves)
        constexpr int LDH = 264;   // 256 + 8 pad
        unsigned short* XC = (unsigned short*)smem;
        const int bm = blockIdx.x;
        // stage Xcat = [interp(x) | xs1] for rows bm*64..+64
        for (int id = tid; id < 3072; id += 256) {
            int row = id / 48, c0 = (id % 48) * 8;
            int gr = bm * 64 + row;
            unsigned short o[8];
            if (c0 < kC2) {
                int j0 = i1d[gr * 3 + 0], j1 = i1d[gr * 3 + 1], j2 = i1d[gr * 3 + 2];
                float ww0 = w1d[gr * 3 + 0], ww1 = w1d[gr * 3 + 1], ww2 = w1d[gr * 3 + 2];
                float a0[8], a1[8], a2[8];
                ld8(x, (long)j0 * kC2 + c0, f32, a0);
                ld8(x, (long)j1 * kC2 + c0, f32, a1);
                ld8(x, (long)j2 * kC2 + c0, f32, a2);
                #pragma unroll
                for (int j = 0; j < 8; j++)
                    o[j] = f2bs(ww0 * a0[j] + ww1 * a1[j] + ww2 * a2[j]);
            } else {
                float s8[8];
                ld8(xs1, (long)gr * kC1 + (c0 - kC2), f32, s8);
                #pragma unroll
                for (int j = 0; j < 8; j++) o[j] = f2bs(s8[j]);
            }
            *(uint4*)&XC[row * LDX + c0] = pack8(o);
        }
        __syncthreads();

        const int lane = tid & 63, wv = tid >> 6;
        const int l16 = lane & 15, quad = lane >> 4;
        v4f acc[16];
        #pragma unroll
        for (int t = 0; t < 16; t++) acc[t] = (v4f){0.f, 0.f, 0.f, 0.f};
        #pragma unroll 1
        for (int k0 = 0; k0 < 384; k0 += 32) {
            const v8s a = *(const v8s*)&XC[(wv * 16 + l16) * LDX + k0 + quad * 8];
            int kg = k0 + quad * 8;
            #pragma unroll
            for (int t = 0; t < 16; t++) {
                int colg = t * 16 + l16;
                const v8s bfr = *(const v8s*)&WT0a[(long)colg * 384 + kg];
                acc[t] = __builtin_amdgcn_mfma_f32_16x16x32_bf16(a, bfr, acc[t], 0, 0, 0);
            }
        }
        __syncthreads();   // XC dead; reuse smem for H1 tile
        unsigned short* Hs = (unsigned short*)smem;
        #pragma unroll
        for (int t = 0; t < 16; t++) {
            int c = t * 16 + l16;
            float bb = rdIn(b0a, c, f32);
            #pragma unroll
            for (int i = 0; i < 4; i++)
                Hs[(wv * 16 + quad * 4 + i) * LDH + c] = f2bs(tanhf(acc[t][i] + bb));
        }
        __syncthreads();

        v4f acc2[8];
        #pragma unroll
        for (int t = 0; t < 8; t++) acc2[t] = (v4f){0.f, 0.f, 0.f, 0.f};
        #pragma unroll 1
        for (int k0 = 0; k0 < 256; k0 += 32) {
            const v8s a = *(const v8s*)&Hs[(wv * 16 + l16) * LDH + k0 + quad * 8];
            int kg = k0 + quad * 8;
            #pragma unroll
            for (int t = 0; t < 8; t++) {
                int colg = t * 16 + l16;
                const v8s bfr = *(const v8s*)&WT0b[(long)colg * 256 + kg];
                acc2[t] = __builtin_amdgcn_mfma_f32_16x16x32_bf16(a, bfr, acc2[t], 0, 0, 0);
            }
        }
        #pragma unroll
        for (int t = 0; t < 8; t++) {
            int c = t * 16 + l16;
            float bb = rdIn(b0b, c, f32);
            #pragma unroll
            for (int i = 0; i < 4; i++) {
                int gr = bm * 64 + wv * 16 + quad * 4 + i;
                float v = tanhf(acc2[t][i] + bb) * g0[(gr >> 11) * 128 + c];
                X1[(long)gr * 128 + c] = f2bs(v);
            }
        }
    } else {
        // ================= layer-2 grid kNN (proven) =================
        constexpr int NS = kN1, NT = kN0, G = 8, SPLIT = 8;
        constexpr int G3 = G * G * G;
        constexpr float h = 1.0f / (float)G;
        constexpr int TPT = 256 / SPLIT;
        constexpr int BPS = NT / TPT;
        float4* sp = (float4*)smem;                    // 32768 B
        int* cs = (int*)(smem + 32768);                // 2052 B
        const int vb = blockIdx.x - 128;
        const int tLoc = tid >> 3;
        const int spl  = tid & (SPLIT - 1);
        const int smp = vb / BPS;
        const int blk = vb % BPS;
        for (int i = tid; i < NS; i += 256) sp[i] = ptsG[(long)smp * NS + i];
        for (int i = tid; i < G3 + 1; i += 256) cs[i] = cstG[smp * (G3 + 1) + i];
        __syncthreads();

        float4 q = ptsT[(long)smp * NT + blk * TPT + tLoc];
        float px = q.x, py = q.y, pz = q.z;
        const int jloc = __float_as_int(q.w);
        int cx = min(G - 1, max(0, (int)(px * (float)G)));
        int cy = min(G - 1, max(0, (int)(py * (float)G)));
        int cz = min(G - 1, max(0, (int)(pz * (float)G)));
        float d0 = 1e30f, d1 = 1e30f, d2 = 1e30f;
        int i0 = 0x7FFFFFFF, i1 = 0x7FFFFFFF, i2 = 0x7FFFFFFF;

        auto insert = [&](float d, int j) {
            bool l0 = (d < d0) || (d == d0 && j < i0);
            bool l1 = (d < d1) || (d == d1 && j < i1);
            bool l2 = (d < d2) || (d == d2 && j < i2);
            float nd2 = l1 ? d1 : (l2 ? d : d2);
            int   ni2 = l1 ? i1 : (l2 ? j : i2);
            float nd1 = l0 ? d0 : (l1 ? d : d1);
            int   ni1 = l0 ? i0 : (l1 ? j : i1);
            d2 = nd2; i2 = ni2; d1 = nd1; i1 = ni1;
            d0 = l0 ? d : d0; i0 = l0 ? j : i0;
        };
        auto scanCell = [&](int cell) {
            int s = cs[cell], e = cs[cell + 1];
            for (int t = s + spl; t < e; t += SPLIT) {
                float4 c = sp[t];
                int j = __float_as_int(c.w);
                float dx = px - c.x, dy = py - c.y, dz = pz - c.z;
                float d = ((dx * dx) + (dy * dy)) + (dz * dz);
                insert(d, j);
            }
        };
        auto merge8 = [&]() {
            #pragma unroll
            for (int m = 1; m < SPLIT; m <<= 1) {
                float pd0 = __shfl_xor(d0, m), pd1 = __shfl_xor(d1, m), pd2 = __shfl_xor(d2, m);
                int   pi0 = __shfl_xor(i0, m), pi1 = __shfl_xor(i1, m), pi2 = __shfl_xor(i2, m);
                if (pi0 != i0 && pi0 != i1 && pi0 != i2) insert(pd0, pi0);
                if (pi1 != i0 && pi1 != i1 && pi1 != i2) insert(pd1, pi1);
                if (pi2 != i0 && pi2 != i1 && pi2 != i2) insert(pd2, pi2);
            }
        };

        #pragma unroll 1
        for (int o = 0; o < 27; o++) {
            int ox = o % 3 - 1, oy = (o / 3) % 3 - 1, oz = o / 9 - 1;
            int X = cx + ox, Y = cy + oy, Z = cz + oz;
            if (X < 0 || X >= G || Y < 0 || Y >= G || Z < 0 || Z >= G) continue;
            scanCell((Z * G + Y) * G + X);
        }
        merge8();

        #pragma unroll 1
        for (int s = 2; s < G; s++) {
            float rm = ((float)(s - 1) * h);
            float ringMin = rm * rm * 0.9999f;
            if (d2 < ringMin) break;
            #pragma unroll 1
            for (int oz = -s; oz <= s; oz++) {
                int Z = cz + oz; if (Z < 0 || Z >= G) continue;
                int az = oz < 0 ? -oz : oz;
                #pragma unroll 1
                for (int oy = -s; oy <= s; oy++) {
                    int Y = cy + oy; if (Y < 0 || Y >= G) continue;
                    int ay = oy < 0 ? -oy : oy;
                    bool outer = (az == s) || (ay == s);
                    #pragma unroll 1
                    for (int ox = -s; ox <= s; ox++) {
                        int ax = ox < 0 ? -ox : ox;
                        if (!outer && ax != s) continue;
                        int X = cx + ox; if (X < 0 || X >= G) continue;
                        float lx = (float)X * h, ly = (float)Y * h, lz = (float)Z * h;
                        float ex = fmaxf(0.f, fmaxf(lx - px, px - (lx + h)));
                        float ey = fmaxf(0.f, fmaxf(ly - py, py - (ly + h)));
                        float ez = fmaxf(0.f, fmaxf(lz - pz, pz - (lz + h)));
                        float md = ((ex * ex) + (ey * ey)) + (ez * ez);
                        if (md * 0.9999f > d2) continue;
                        scanCell((Z * G + Y) * G + X);
                    }
                }
            }
            merge8();
        }

        if (spl == 0) {
            float wa = 1.f / fmaxf(d0, 1e-16f);
            float wb = 1.f / fmaxf(d1, 1e-16f);
            float wc = 1.f / fmaxf(d2, 1e-16f);
            float sw = wa + wb + wc;
            long tg = (long)smp * NT + jloc;
            i0d[tg * 3 + 0] = smp * NS + i0;
            i0d[tg * 3 + 1] = smp * NS + i1;
            i0d[tg * 3 + 2] = smp * NS + i2;
            w0d[tg * 3 + 0] = wa / sw;
            w0d[tg * 3 + 1] = wb / sw;
            w0d[tg * 3 + 2] = wc / sw;
        }
    }
}

// ===========================================================================
// PHASE 3 (one launch, 256 thr): fused layer-2 MLP on a 64-row slab:
// gather-interp from X1/xs0 -> LDS, GEMM K=192 -> tanh -> LDS,
// GEMM K=128 -> *g1 -> fp32 out. XC2/H2 never touch global.
// ===========================================================================
__global__ __launch_bounds__(256) void fpno_p3(
    const unsigned short* __restrict__ X1, const void* __restrict__ xs0,
    const unsigned short* __restrict__ WT1a, const unsigned short* __restrict__ WT1b,
    const void* __restrict__ b1a, const void* __restrict__ b1b,
    const float* __restrict__ g1,
    const int* __restrict__ i0d, const float* __restrict__ w0d,
    const int* __restrict__ flagp,
    float* __restrict__ out) {
    #pragma clang fp contract(off)
    constexpr int LDX = 200;   // 192 + 8 pad (halves)
    constexpr int LDH = 136;   // 128 + 8 pad
    __shared__ __align__(16) char smem[25600];
    const int f32 = *flagp;
    const int tid = threadIdx.x;
    unsigned short* XC = (unsigned short*)smem;
    const int bm = blockIdx.x;

    for (int id = tid; id < 1536; id += 256) {
        int row = id / 24, c0 = (id % 24) * 8;
        int gr = bm * 64 + row;
        unsigned short o[8];
        if (c0 < kC1) {
            int j0 = i0d[gr * 3 + 0], j1 = i0d[gr * 3 + 1], j2 = i0d[gr * 3 + 2];
            float ww0 = w0d[gr * 3 + 0], ww1 = w0d[gr * 3 + 1], ww2 = w0d[gr * 3 + 2];
            float a0[8], a1[8], a2[8];
            ld8(X1, (long)j0 * kC1 + c0, 0, a0);
            ld8(X1, (long)j1 * kC1 + c0, 0, a1);
            ld8(X1, (long)j2 * kC1 + c0, 0, a2);
            #pragma unroll
            for (int j = 0; j < 8; j++)
                o[j] = f2bs(ww0 * a0[j] + ww1 * a1[j] + ww2 * a2[j]);
        } else {
            float s8[8];
            ld8(xs0, (long)gr * kC0 + (c0 - kC1), f32, s8);
            #pragma unroll
            for (int j = 0; j < 8; j++) o[j] = f2bs(s8[j]);
        }
        *(uint4*)&XC[row * LDX + c0] = pack8(o);
    }
    __syncthreads();

    const int lane = tid & 63, wv = tid >> 6;
    const int l16 = lane & 15, quad = lane >> 4;
    v4f acc[8];
    #pragma unroll
    for (int t = 0; t < 8; t++) acc[t] = (v4f){0.f, 0.f, 0.f, 0.f};
    #pragma unroll 1
    for (int k0 = 0; k0 < 192; k0 += 32) {
        const v8s a = *(const v8s*)&XC[(wv * 16 + l16) * LDX + k0 + quad * 8];
        int kg = k0 + quad * 8;
        #pragma unroll
        for (int t = 0; t < 8; t++) {
            int colg = t * 16 + l16;
            const v8s bfr = *(const v8s*)&WT1a[(long)colg * 192 + kg];
            acc[t] = __builtin_amdgcn_mfma_f32_16x16x32_bf16(a, bfr, acc[t], 0, 0, 0);
        }
    }
    __syncthreads();
    unsigned short* Hs = (unsigned short*)smem;
    #pragma unroll
    for (int t = 0; t < 8; t++) {
        int c = t * 16 + l16;
        float bb = rdIn(b1a, c, f32);
        #pragma unroll
        for (int i = 0; i < 4; i++)
            Hs[(wv * 16 + quad * 4 + i) * LDH + c] = f2bs(tanhf(acc[t][i] + bb));
    }
    __syncthreads();

    v4f acc2[4];
    #pragma unroll
    for (int t = 0; t < 4; t++) acc2[t] = (v4f){0.f, 0.f, 0.f, 0.f};
    #pragma unroll 1
    for (int k0 = 0; k0 < 128; k0 += 32) {
        const v8s a = *(const v8s*)&Hs[(wv * 16 + l16) * LDH + k0 + quad * 8];
        int kg = k0 + quad * 8;
        #pragma unroll
        for (int t = 0; t < 4; t++) {
            int colg = t * 16 + l16;
            const v8s bfr = *(const v8s*)&WT1b[(long)colg * 128 + kg];
            acc2[t] = __builtin_amdgcn_mfma_f32_16x16x32_bf16(a, bfr, acc2[t], 0, 0, 0);
        }
    }
    #pragma unroll
    for (int t = 0; t < 4; t++) {
        int c = t * 16 + l16;
        float bb = rdIn(b1b, c, f32);
        #pragma unroll
        for (int i = 0; i < 4; i++) {
            int gr = bm * 64 + wv * 16 + quad * 4 + i;
            float v = (acc2[t][i] + bb) * g1[(gr >> 13) * 64 + c];
            out[(long)gr * 64 + c] = v;
        }
    }
}

// ===========================================================================
extern "C" void kernel_launch(void* const* d_in, const int* in_sizes, int n_in,
                              void* d_out, int out_size, void* d_ws, size_t ws_size,
                              hipStream_t stream) {
    (void)out_size;
    float* out = (float*)d_out;   // fp32 output buffer
    const int R1 = kB * kN1;  // 8192
    const int R0 = kB * kN0;  // 32768

    static const int kExp[22] = {
        256, 524288, 6144, 2048, 1048576, 24576, 8192, 2097152, 98304, 32768,
        98304, 256, 32768, 128, 8192, 128, 24576, 128, 8192, 64, 4096, 64};
    if (n_in != 22) { fpno_guard<<<1, 64, 0, stream>>>(3072.0f, out); return; }
    for (int i = 0; i < 22; i++) {
        if (in_sizes[i] != kExp[i]) {
            fpno_guard<<<1, 64, 0, stream>>>(1024.0f + 8.0f * i, out);
            return;
        }
    }

    // ---- workspace (~3.6 MB) ----
    char* base = (char*)d_ws;
    size_t off = 0;
    auto alloc = [&](size_t bytes) {
        off = (off + 255) & ~(size_t)255; size_t o = off; off += bytes; return o;
    };
    int*            flag = (int*)(base + alloc(4));
    float*          g0   = (float*)(base + alloc(kB * 128 * 4));
    float*          g1   = (float*)(base + alloc(kB * 64 * 4));
    int*            i1d  = (int*)(base + alloc((size_t)R1 * 3 * 4));
    float*          w1d  = (float*)(base + alloc((size_t)R1 * 3 * 4));
    int*            i0d  = (int*)(base + alloc((size_t)R0 * 3 * 4));
    float*          w0d  = (float*)(base + alloc((size_t)R0 * 3 * 4));
    float4*         ptsG = (float4*)(base + alloc((size_t)kB * kN1 * 16));        // 128 KB
    int*            cstG = (int*)(base + alloc((size_t)kB * (512 + 1) * 4));
    float4*         ptsT = (float4*)(base + alloc((size_t)kB * kN0 * 16));        // 512 KB
    int*            cstT = (int*)(base + alloc((size_t)kB * (512 + 1) * 4));
    unsigned short* WT   = (unsigned short*)(base + alloc(163840 * 2));           // 320 KB
    unsigned short* X1   = (unsigned short*)(base + alloc((size_t)R1 * 128 * 2)); // 2 MB
    if (ws_size < off) { fpno_guard<<<1, 64, 0, stream>>>(2048.0f, out); return; }
    unsigned short* WT0a = WT;            // 256 x 384
    unsigned short* WT0b = WT + 98304;    // 128 x 256
    unsigned short* WT1a = WT + 131072;   // 128 x 192
    unsigned short* WT1b = WT + 155648;   // 64 x 128

    const void* par  = d_in[0];
    const void* x    = d_in[1];
    const void* pos  = d_in[2];
    const void* xs1  = d_in[4];
    const void* pos1 = d_in[5];
    const void* xs0  = d_in[7];
    const void* pos0 = d_in[8];
    const int*  bt0  = (const int*)d_in[9];
    const void *W0a = d_in[10], *b0a = d_in[11], *W0b = d_in[12], *b0b = d_in[13];
    const void *Wp0 = d_in[14], *bp0 = d_in[15];
    const void *W1a = d_in[16], *b1a = d_in[17], *W1b = d_in[18], *b1b = d_in[19];
    const void *Wp1 = d_in[20], *bp1 = d_in[21];

    // PHASE 1: wconv | gates | layer-1 kNN | bins | tail  (714 blocks x 512)
    fpno_p1<<<714, 512, 0, stream>>>(
        (const unsigned int*)pos, pos, pos1, pos0,
        W0a, W0b, W1a, W1b, par, Wp0, bp0, Wp1, bp1, bt0,
        flag, WT, g0, g1, i1d, w1d, ptsG, cstG, ptsT, cstT, out);

    // PHASE 2: fused layer-1 MLP (128 blocks) | layer-2 kNN (1024 blocks)
    fpno_p2<<<1152, 256, 0, stream>>>(
        x, xs1, WT0a, WT0b, b0a, b0b, g0, i1d, w1d,
        ptsG, cstG, ptsT, flag, X1, i0d, w0d);

    // PHASE 3: fused layer-2 MLP -> fp32 out  (512 blocks)
    fpno_p3<<<512, 256, 0, stream>>>(
        X1, xs0, WT1a, WT1b, b1a, b1b, g1, i0d, w0d, flag, out);
}